// Round 4
// baseline (914.483 us; speedup 1.0000x reference)
//
#include <hip/hip_runtime.h>

#define HIDDEN 2048
#define QUANT  16
#define BATCH  8192
#define HALFD  1024

// GEMM geometry: 256x128 tile, ring-3 of BK=32 K-tiles, 4 waves (2m x 2n),
// 2 blocks/CU (72 KB LDS each).
#define BM 256
#define BN 128
#define BKT 32
#define NT (HIDDEN / BKT)        // 64 K-tiles
#define A_H (BM * BKT)           // 8192 halfs = 16 KB per A slot
#define B_H (BN * BKT)           // 4096 halfs =  8 KB per B slot
#define SLOT (A_H + B_H)         // 24 KB; x3 slots = 72 KB

typedef _Float16 half8  __attribute__((ext_vector_type(8)));
typedef float    floatx16 __attribute__((ext_vector_type(16)));

__device__ __forceinline__ void load_lds16(const void* gptr, void* lptr) {
  __builtin_amdgcn_global_load_lds(
      (const __attribute__((address_space(1))) void*)gptr,
      (__attribute__((address_space(3))) void*)lptr, 16, 0, 0);
}

// exact-GELU via Abramowitz-Stegun 7.1.26 erf (|eps_erf| <= 1.5e-7)
__device__ __forceinline__ float gelu_exact(float v) {
  const float z  = 0.7071067811865476f * v;
  const float az = fabsf(z);
  const float t  = __builtin_amdgcn_rcpf(1.0f + 0.3275911f * az);
  const float p  = t * (0.254829592f +
                   t * (-0.284496736f +
                   t * (1.421413741f +
                   t * (-1.453152027f +
                   t * 1.061405429f))));
  float er = 1.0f - p * __expf(-az * az);
  er = copysignf(er, z);
  return 0.5f * v * (1.0f + er);
}

// ---- fused prep: x fp32->fp16 | W1 transpose->fp16 | out=b2 ----
// grid-partitioned single kernel: removes 2 launch gaps, overlaps the
// three independent memory streams.
#define PREP_CONV 8192          // convert blocks
#define PREP_TRAN 16384         // transpose blocks
#define PREP_INIT 512           // init blocks
__global__ __launch_bounds__(256) void prep_kernel(
    const float* __restrict__ x,  _Float16* __restrict__ xh,
    const float* __restrict__ W1, _Float16* __restrict__ W1T,
    const float* __restrict__ b2, float* __restrict__ out) {
  __shared__ float tile[64][33];
  const int blk = blockIdx.x;
  const int t = threadIdx.x;
  if (blk < PREP_CONV) {
    const int i = (blk * 256 + t) * 8;
    const float4 a = *(const float4*)(x + i);
    const float4 b = *(const float4*)(x + i + 4);
    half8 h;
    h[0] = (_Float16)a.x; h[1] = (_Float16)a.y; h[2] = (_Float16)a.z; h[3] = (_Float16)a.w;
    h[4] = (_Float16)b.x; h[5] = (_Float16)b.y; h[6] = (_Float16)b.z; h[7] = (_Float16)b.w;
    *(half8*)(xh + i) = h;
  } else if (blk < PREP_CONV + PREP_TRAN) {
    const int bid = blk - PREP_CONV;
    const int q  = bid >> 10;
    const int h0 = ((bid >> 5) & 31) * 64;
    const int n0 = (bid & 31) * 32;
    const float* src = W1 + (size_t)q * HIDDEN * HALFD;
    _Float16*    dst = W1T + (size_t)q * HALFD * HIDDEN;
    const int lr = t >> 3;
    const int lc = (t & 7) * 4;
    #pragma unroll
    for (int j = 0; j < 2; ++j) {
      const float4 v = *(const float4*)(src + (size_t)(h0 + lr + 32 * j) * HALFD + n0 + lc);
      tile[lr + 32 * j][lc + 0] = v.x;
      tile[lr + 32 * j][lc + 1] = v.y;
      tile[lr + 32 * j][lc + 2] = v.z;
      tile[lr + 32 * j][lc + 3] = v.w;
    }
    __syncthreads();
    const int sn = t >> 3;
    const int sh = (t & 7) * 8;
    half8 v;
    #pragma unroll
    for (int c = 0; c < 8; ++c) v[c] = (_Float16)tile[sh + c][sn];
    *(half8*)(dst + (size_t)(n0 + sn) * HIDDEN + h0 + sh) = v;
  } else {
    const int i = (blk - PREP_CONV - PREP_TRAN) * 256 + t;
    out[i] = b2[i & (QUANT - 1)];
  }
}

// ---- fused GEMM + bias + GELU + W2-reduction ----
// R3's register-read-ahead pipeline on a ring-3, sized for 2 blocks/CU so
// two independent barrier domains overlap each other's waits.
// Per tile t (2 phases):
//  P1: compute (t,ks0)=r0; read (t,ks1)->r1; stage A(t+2); lgkmcnt(6);
//      8 MFMA; vmcnt(4) [retires B(t+1) -> tile t+1 resident]; s_barrier
//  P2: compute (t,ks1)=r1; read (t+1,ks0)->r0; stage B(t+2); lgkmcnt(6);
//      8 MFMA; s_barrier
// vmcnt is per-wave; the following s_barrier makes residency block-wide.
// Slot-overwrite safety: slot(t-1)'s last reads complete before t-1.P2's
// barrier (lgkmcnt), and the overwriting stage is issued in t.P1.
// LDS swizzle: logical kgroup kg at phys slot kg ^ ((row>>1)&3); inverse
// applied on the GLOBAL source, LDS dest linear (gload_lds requirement).
__global__ __launch_bounds__(256, 2) void qhead_gemm_kernel(
    const _Float16* __restrict__ A,   // [BATCH][HIDDEN] fp16
    const _Float16* __restrict__ BT,  // [QUANT][HALFD][HIDDEN] fp16
    const float* __restrict__ b1,     // [QUANT][HALFD]
    const float* __restrict__ W2,     // [QUANT][HALFD]
    float* __restrict__ out) {        // [BATCH][QUANT]
  extern __shared__ _Float16 lds[];   // 3 * 24 KB = 72 KB

  const int tid  = threadIdx.x;
  const int lane = tid & 63;
  const int wave = tid >> 6;
  const int wm = wave >> 1, wn = wave & 1;   // 2 x 2 waves
  const int r31 = lane & 31, l5 = lane >> 5;
  const int fsw = (r31 >> 1) & 3;            // read-side swizzle term

  // XCD-bijective block swizzle (4096 % 8 == 0)
  const int flat = blockIdx.x;
  const int wg = (flat & 7) * 512 + (flat >> 3);
  const int mb = wg >> 7;          // 0..31 row-panel (concurrent window shares it)
  const int rest = wg & 127;
  const int q  = rest >> 3;        // head
  const int nb = rest & 7;         // 128-col block within head
  const int m0 = mb << 8;

  const _Float16* Ablk = A + (size_t)m0 * HIDDEN;
  const _Float16* Bblk = BT + ((size_t)q * HALFD + nb * BN) * HIDDEN;

  // Staging: chunk c = tid + 256*i -> (row = c>>2, phys slot = c&3).
  // (row>>1)&3 is i-invariant (64*i even in row, 32*i == 0 mod 4), so the
  // per-thread inverse swizzle is constant: skg = (tid&3) ^ ((tid>>3)&3).
  const int skg = (tid & 3) ^ ((tid >> 3) & 3);
  const _Float16* agp = Ablk + (size_t)(tid >> 2) * HIDDEN + skg * 8;
  const _Float16* bgp = Bblk + (size_t)(tid >> 2) * HIDDEN + skg * 8;

  // frag row bases (half-index, row stride BKT=32 halfs)
  int aoff[4], boff[2];
  #pragma unroll
  for (int mf = 0; mf < 4; ++mf) aoff[mf] = (wm * 128 + mf * 32 + r31) * BKT;
  #pragma unroll
  for (int nf = 0; nf < 2; ++nf) boff[nf] = A_H + (wn * 64 + nf * 32 + r31) * BKT;

  floatx16 acc[4][2];
  #pragma unroll
  for (int mf = 0; mf < 4; ++mf)
    #pragma unroll
    for (int nf = 0; nf < 2; ++nf)
      #pragma unroll
      for (int i = 0; i < 16; ++i) acc[mf][nf][i] = 0.f;

  half8 r0[6], r1[6];

#define STAGE_A(SB, ts_) do {                                              \
    const int ts_a = (ts_);                                                \
    const int kc_a = ((ts_a < NT) ? ts_a : (ts_a - NT)) * BKT;             \
    _Float16* ld_a = (SB) + tid * 8;                                       \
    load_lds16(agp + kc_a, ld_a);                                          \
    load_lds16(agp + kc_a + (size_t)64 * HIDDEN,  ld_a + 2048);            \
    load_lds16(agp + kc_a + (size_t)128 * HIDDEN, ld_a + 4096);            \
    load_lds16(agp + kc_a + (size_t)192 * HIDDEN, ld_a + 6144);            \
  } while (0)

#define STAGE_B(SB, ts_) do {                                              \
    const int ts_b = (ts_);                                                \
    const int kc_b = ((ts_b < NT) ? ts_b : (ts_b - NT)) * BKT;             \
    _Float16* ld_b = (SB) + A_H + tid * 8;                                 \
    load_lds16(bgp + kc_b, ld_b);                                          \
    load_lds16(bgp + kc_b + (size_t)64 * HIDDEN, ld_b + 2048);             \
  } while (0)

// CUR: frags to compute now; NXT: issue reads for next phase from LSN/KSN.
#define PHASE(CUR, NXT, LSN, KSN, STAGE_STMT, DO_VM4) do {                 \
    const _Float16* lsn_ = (LSN);                                          \
    const int pn_ = ((((KSN) << 1) | l5) ^ fsw) << 3;                      \
    NXT[0] = *(const half8*)(lsn_ + aoff[0] + pn_);                        \
    NXT[1] = *(const half8*)(lsn_ + aoff[1] + pn_);                        \
    NXT[2] = *(const half8*)(lsn_ + aoff[2] + pn_);                        \
    NXT[3] = *(const half8*)(lsn_ + aoff[3] + pn_);                        \
    NXT[4] = *(const half8*)(lsn_ + boff[0] + pn_);                        \
    NXT[5] = *(const half8*)(lsn_ + boff[1] + pn_);                        \
    STAGE_STMT;                                                            \
    asm volatile("s_waitcnt lgkmcnt(6)" ::: "memory");                     \
    __builtin_amdgcn_sched_barrier(0);                                     \
    __builtin_amdgcn_s_setprio(1);                                         \
    acc[0][0] = __builtin_amdgcn_mfma_f32_32x32x16_f16(CUR[0], CUR[4], acc[0][0], 0, 0, 0); \
    acc[0][1] = __builtin_amdgcn_mfma_f32_32x32x16_f16(CUR[0], CUR[5], acc[0][1], 0, 0, 0); \
    acc[1][0] = __builtin_amdgcn_mfma_f32_32x32x16_f16(CUR[1], CUR[4], acc[1][0], 0, 0, 0); \
    acc[1][1] = __builtin_amdgcn_mfma_f32_32x32x16_f16(CUR[1], CUR[5], acc[1][1], 0, 0, 0); \
    acc[2][0] = __builtin_amdgcn_mfma_f32_32x32x16_f16(CUR[2], CUR[4], acc[2][0], 0, 0, 0); \
    acc[2][1] = __builtin_amdgcn_mfma_f32_32x32x16_f16(CUR[2], CUR[5], acc[2][1], 0, 0, 0); \
    acc[3][0] = __builtin_amdgcn_mfma_f32_32x32x16_f16(CUR[3], CUR[4], acc[3][0], 0, 0, 0); \
    acc[3][1] = __builtin_amdgcn_mfma_f32_32x32x16_f16(CUR[3], CUR[5], acc[3][1], 0, 0, 0); \
    __builtin_amdgcn_s_setprio(0);                                         \
    __builtin_amdgcn_sched_barrier(0);                                     \
    if (DO_VM4) asm volatile("s_waitcnt vmcnt(4)" ::: "memory");           \
    asm volatile("s_barrier" ::: "memory");                                \
  } while (0)

  // prologue: stage tiles 0,1 (12 loads); vmcnt(6) retires A0,B0 -> tile0
  // resident (per-wave), barrier makes it block-wide.
  STAGE_A(lds, 0); STAGE_B(lds, 0);
  STAGE_A(lds + SLOT, 1); STAGE_B(lds + SLOT, 1);
  asm volatile("s_waitcnt vmcnt(6)\n\ts_barrier" ::: "memory");

  // prime r0 with tile0, ks=0
  {
    const int p0i = (l5 ^ fsw) << 3;
    r0[0] = *(const half8*)(lds + aoff[0] + p0i);
    r0[1] = *(const half8*)(lds + aoff[1] + p0i);
    r0[2] = *(const half8*)(lds + aoff[2] + p0i);
    r0[3] = *(const half8*)(lds + aoff[3] + p0i);
    r0[4] = *(const half8*)(lds + boff[0] + p0i);
    r0[5] = *(const half8*)(lds + boff[1] + p0i);
  }

  const _Float16* p0 = lds;            // slot of tile t
  const _Float16* p1 = lds + SLOT;     // slot of tile t+1
  _Float16*       p2 = lds + 2 * SLOT; // stage dest (tile t+2)

  #pragma unroll 3
  for (int t = 0; t < NT; ++t) {
    // P1: compute (t,ks0); read (t,ks1); stage A(t+2); vmcnt(4) => tile t+1
    PHASE(r0, r1, p0, 1, STAGE_A(p2, t + 2), 1);
    // P2: compute (t,ks1); read (t+1,ks0); stage B(t+2)
    PHASE(r1, r0, p1, 0, STAGE_B(p2, t + 2), 0);
    const _Float16* tmp = p0; p0 = p1; p1 = p2; p2 = (_Float16*)tmp;
  }
#undef PHASE
#undef STAGE_A
#undef STAGE_B

  // ---- epilogue: bias + exact GELU + *W2, reduce over this wave's 64 columns ----
  // 32x32 C/D layout: col = lane&31, row = (reg&3) + 8*(reg>>2) + 4*(lane>>5)
  const int colb = nb * BN + wn * 64;
  #pragma unroll
  for (int mf = 0; mf < 4; ++mf) {
    float rs[16];
    #pragma unroll
    for (int r = 0; r < 16; ++r) rs[r] = 0.f;
    #pragma unroll
    for (int nf = 0; nf < 2; ++nf) {
      const int ncol = colb + nf * 32 + r31;
      const float b1v = b1[q * HALFD + ncol];
      const float w2v = W2[q * HALFD + ncol];
      #pragma unroll
      for (int r = 0; r < 16; ++r)
        rs[r] += gelu_exact(acc[mf][nf][r] + b1v) * w2v;
    }
    // butterfly-sum across the 32 column-lanes (low 5 lane bits)
    #pragma unroll
    for (int r = 0; r < 16; ++r) {
      float v = rs[r];
      v += __shfl_xor(v, 1, 64);
      v += __shfl_xor(v, 2, 64);
      v += __shfl_xor(v, 4, 64);
      v += __shfl_xor(v, 8, 64);
      v += __shfl_xor(v, 16, 64);
      rs[r] = v;
    }
    if (r31 == 0) {
      const int mbase = m0 + wm * 128 + mf * 32 + 4 * l5;
      #pragma unroll
      for (int r = 0; r < 16; ++r) {
        const int mrow = mbase + (r & 3) + 8 * (r >> 2);
        atomicAdd(&out[(size_t)mrow * QUANT + q], rs[r]);
      }
    }
  }
}

extern "C" void kernel_launch(void* const* d_in, const int* in_sizes, int n_in,
                              void* d_out, int out_size, void* d_ws, size_t ws_size,
                              hipStream_t stream) {
  const float* x  = (const float*)d_in[0];
  const float* W1 = (const float*)d_in[1];
  const float* b1 = (const float*)d_in[2];
  const float* W2 = (const float*)d_in[3];
  const float* b2 = (const float*)d_in[4];
  float* out = (float*)d_out;

  _Float16* xh  = (_Float16*)d_ws;                                   // 32 MB
  _Float16* w1t = (_Float16*)((char*)d_ws +
                  (size_t)BATCH * HIDDEN * sizeof(_Float16));        // 64 MB

  static int lds_cfg = 0;
  if (!lds_cfg) {
    hipFuncSetAttribute(reinterpret_cast<const void*>(qhead_gemm_kernel),
                        hipFuncAttributeMaxDynamicSharedMemorySize, 3 * SLOT * 2);
    lds_cfg = 1;
  }

  prep_kernel<<<PREP_CONV + PREP_TRAN + PREP_INIT, 256, 0, stream>>>(
      x, xh, W1, w1t, b2, out);
  qhead_gemm_kernel<<<dim3(BATCH / BM * (QUANT * HALFD / BN)), 256,
                      3 * SLOT * 2, stream>>>(xh, w1t, b1, W2, out);
}